// Round 1
// baseline (172.802 us; speedup 1.0000x reference)
//
#include <hip/hip_runtime.h>

// Problem constants
#define NTOK   32768
#define CDIM   128
#define NH     8
#define NCHUNK 64     // split-K chunks for ktv reduction
#define CHROWS 512    // rows per chunk in k_ktv
#define SC     64     // rows per sub-chunk (LDS tile)

typedef __bf16 bf16;
typedef __bf16 bf16x4v __attribute__((ext_vector_type(4)));
typedef __bf16 bf16x8v __attribute__((ext_vector_type(8)));
typedef float  f32x4   __attribute__((ext_vector_type(4)));

__device__ __forceinline__ f32x4 mfma16(bf16x8v a, bf16x8v b, f32x4 c) {
  return __builtin_amdgcn_mfma_f32_16x16x32_bf16(a, b, c, 0, 0, 0);
}

// sum across the 16-lane group (lanes differing in bits 0..3)
__device__ __forceinline__ float xred16(float v) {
  v += __shfl_xor(v, 1);
  v += __shfl_xor(v, 2);
  v += __shfl_xor(v, 4);
  v += __shfl_xor(v, 8);
  return v;
}

// ---------------------------------------------------------------------------
// k_prep: convert Wq/Wk/Wv to bf16; W2[h] = vmap_w @ Wv[h]; b2 = vmap_w@Wv_b + vmap_b
// grid: 1024 blocks (h,o), 128 threads (i)
// ---------------------------------------------------------------------------
__global__ void __launch_bounds__(128) k_prep(
    const float* __restrict__ Wq, const float* __restrict__ Wk,
    const float* __restrict__ Wv, const float* __restrict__ Wv_b,
    const float* __restrict__ vmw, const float* __restrict__ vmb,
    bf16* __restrict__ wq, bf16* __restrict__ wk, bf16* __restrict__ wv,
    bf16* __restrict__ w2, float* __restrict__ b2)
{
  const int h = blockIdx.x >> 7, o = blockIdx.x & 127;
  const int i = threadIdx.x;
  const int base = (h * CDIM + o) * CDIM;
  wq[base + i] = (bf16)Wq[base + i];
  wk[base + i] = (bf16)Wk[base + i];
  wv[base + i] = (bf16)Wv[base + i];
  float acc = 0.f;
  for (int d = 0; d < CDIM; ++d)
    acc = fmaf(vmw[o * CDIM + d], Wv[(h * CDIM + d) * CDIM + i], acc);
  w2[base + i] = (bf16)acc;
  __shared__ float red[128];
  red[i] = vmw[o * CDIM + i] * Wv_b[h * CDIM + i];
  __syncthreads();
  for (int s = 64; s > 0; s >>= 1) {
    if (i < s) red[i] += red[i + s];
    __syncthreads();
  }
  if (i == 0) b2[h * CDIM + o] = red[0] + vmb[o];
}

// ---------------------------------------------------------------------------
// k_ktv: per (chunk c, head h): ks = src@Wk^T+b, v = src@Wv^T+b, phi(ks),
//        ktv_part[c][h][d][m] = sum_n v[n,d]*phi_ks[n,m],  ksum_part[c][h][m]
// grid: NCHUNK*NH = 512 blocks, 256 threads (4 waves)
// ---------------------------------------------------------------------------
__global__ void __launch_bounds__(256, 2) k_ktv(
    const float* __restrict__ src,
    const bf16* __restrict__ wk, const bf16* __restrict__ wv,
    const float* __restrict__ Wk_b, const float* __restrict__ Wv_b,
    const float* __restrict__ nscale,
    bf16* __restrict__ ktv_part, float* __restrict__ ksum_part)
{
  const int bid = blockIdx.x;
  const int h = bid & 7, c = bid >> 3;
  const int tid = threadIdx.x;
  const int w = tid >> 6, l = tid & 63;
  const int l15 = l & 15, lg = l >> 4;
  const int os = w * 32;   // per-wave o-strip for projection GEMMs

  __shared__ bf16 s_src[SC][136];      // [n][i] bf16, padded (2-way conflicts only)
  __shared__ bf16 s_phiT[128][72];     // [m][n]
  __shared__ bf16 s_vT[128][72];       // [d][n]
  __shared__ float s_red[4][SC][2] __attribute__((aligned(16)));
  __shared__ float s_scale[SC] __attribute__((aligned(16)));

  const float inv_ds = 1.f / (fabsf(nscale[0]) + 1e-6f);
  const f32x4 z4 = {0.f, 0.f, 0.f, 0.f};

  // hoist weight B-fragments + biases (loop-invariant)
  bf16x8v bWk[2][4], bWv[2][4];
  float bK[2], bV[2];
#pragma unroll
  for (int ot = 0; ot < 2; ++ot) {
    const int o = os + ot * 16 + l15;
    const bf16* pk = wk + (h * CDIM + o) * CDIM + lg * 8;
    const bf16* pv = wv + (h * CDIM + o) * CDIM + lg * 8;
#pragma unroll
    for (int kk = 0; kk < 4; ++kk) {
      bWk[ot][kk] = *(const bf16x8v*)(pk + kk * 32);
      bWv[ot][kk] = *(const bf16x8v*)(pv + kk * 32);
    }
    bK[ot] = Wk_b[h * CDIM + o];
    bV[ot] = Wv_b[h * CDIM + o];
  }

  // ktv accumulator: wave quadrant (64x64 of [d=128][m=128])
  const int wd = (w >> 1) * 64, wm = (w & 1) * 64;
  f32x4 acc[4][4];
#pragma unroll
  for (int dt = 0; dt < 4; ++dt)
#pragma unroll
    for (int mt = 0; mt < 4; ++mt) acc[dt][mt] = z4;
  float ksacc[2] = {0.f, 0.f};

  for (int s = 0; s < CHROWS / SC; ++s) {
    const int nb = c * CHROWS + s * SC;
    __syncthreads();
    // stage source tile -> bf16 LDS
#pragma unroll
    for (int j = 0; j < 8; ++j) {
      const int flat = tid + j * 256;
      const int n = flat >> 5, i4 = flat & 31;
      f32x4 v = *(const f32x4*)(src + (nb + n) * CDIM + i4 * 4);
      bf16x4v bv;
      bv[0] = (bf16)v[0]; bv[1] = (bf16)v[1]; bv[2] = (bf16)v[2]; bv[3] = (bf16)v[3];
      *(bf16x4v*)&s_src[n][i4 * 4] = bv;
    }
    __syncthreads();

    // GEMM: ks[n,o], v[n,o] for the wave's o-strip (M=n rows, N=o cols, K=i)
    f32x4 accK[4][2], accV[4][2];
#pragma unroll
    for (int nt = 0; nt < 4; ++nt)
#pragma unroll
      for (int ot = 0; ot < 2; ++ot) { accK[nt][ot] = z4; accV[nt][ot] = z4; }
#pragma unroll
    for (int kk = 0; kk < 4; ++kk) {
      bf16x8v a[4];
#pragma unroll
      for (int nt = 0; nt < 4; ++nt)
        a[nt] = *(const bf16x8v*)&s_src[nt * 16 + l15][kk * 32 + lg * 8];
#pragma unroll
      for (int nt = 0; nt < 4; ++nt)
#pragma unroll
        for (int ot = 0; ot < 2; ++ot) {
          accK[nt][ot] = mfma16(a[nt], bWk[ot][kk], accK[nt][ot]);
          accV[nt][ot] = mfma16(a[nt], bWv[ot][kk], accV[nt][ot]);
        }
    }

    // x^2 in place + per-row (n) strip norms, reduced over the 16-lane group
#pragma unroll
    for (int nt = 0; nt < 4; ++nt)
#pragma unroll
      for (int r = 0; r < 4; ++r) {
        float a2 = 0.f, a4 = 0.f;
#pragma unroll
        for (int ot = 0; ot < 2; ++ot) {
          float x = (fmaxf(accK[nt][ot][r] + bK[ot], 0.f) + 1e-6f) * inv_ds;
          float x2 = x * x;
          accK[nt][ot][r] = x2;
          a2 += x2;
          a4 += x2 * x2;
        }
        a2 = xred16(a2);
        a4 = xred16(a4);
        if (l15 == 0) {
          s_red[w][nt * 16 + lg * 4 + r][0] = a2;
          s_red[w][nt * 16 + lg * 4 + r][1] = a4;
        }
      }
    __syncthreads();
    if (tid < SC) {
      float S2 = s_red[0][tid][0] + s_red[1][tid][0] + s_red[2][tid][0] + s_red[3][tid][0];
      float S4 = s_red[0][tid][1] + s_red[1][tid][1] + s_red[2][tid][1] + s_red[3][tid][1];
      s_scale[tid] = sqrtf(S2) / (sqrtf(S4) + 1e-8f);
    }
    __syncthreads();

    // phi values + biased v -> transposed LDS tiles ([m][n], [d][n])
#pragma unroll
    for (int nt = 0; nt < 4; ++nt) {
      f32x4 sc = *(const f32x4*)&s_scale[nt * 16 + lg * 4];
#pragma unroll
      for (int ot = 0; ot < 2; ++ot) {
        bf16x4v ph, vv;
#pragma unroll
        for (int r = 0; r < 4; ++r) {
          float p = accK[nt][ot][r] * sc[r];
          ksacc[ot] += p;
          ph[r] = (bf16)p;
          vv[r] = (bf16)(accV[nt][ot][r] + bV[ot]);
        }
        const int colb = os + ot * 16 + l15;
        *(bf16x4v*)&s_phiT[colb][nt * 16 + lg * 4] = ph;
        *(bf16x4v*)&s_vT[colb][nt * 16 + lg * 4] = vv;
      }
    }
    __syncthreads();

    // ktv += v^T(phi): M=d (A=s_vT), N=m (B=s_phiT), K=n(=SC)
#pragma unroll
    for (int kk = 0; kk < 2; ++kk) {
      bf16x8v aV[4], bP[4];
#pragma unroll
      for (int dt = 0; dt < 4; ++dt)
        aV[dt] = *(const bf16x8v*)&s_vT[wd + dt * 16 + l15][kk * 32 + lg * 8];
#pragma unroll
      for (int mt = 0; mt < 4; ++mt)
        bP[mt] = *(const bf16x8v*)&s_phiT[wm + mt * 16 + l15][kk * 32 + lg * 8];
#pragma unroll
      for (int dt = 0; dt < 4; ++dt)
#pragma unroll
        for (int mt = 0; mt < 4; ++mt)
          acc[dt][mt] = mfma16(aV[dt], bP[mt], acc[dt][mt]);
    }
  }

  // ksum partial: combine the 4 row-groups, then lanes 0..15 write the strip
#pragma unroll
  for (int ot = 0; ot < 2; ++ot) {
    ksacc[ot] += __shfl_xor(ksacc[ot], 16);
    ksacc[ot] += __shfl_xor(ksacc[ot], 32);
  }
  if (l < 16) {
#pragma unroll
    for (int ot = 0; ot < 2; ++ot)
      ksum_part[(c * NH + h) * CDIM + os + ot * 16 + l] = ksacc[ot];
  }
  // ktv partial store: [c][h][d][m] (bf16)
  bf16* kp = ktv_part + (c * NH + h) * CDIM * CDIM;
#pragma unroll
  for (int dt = 0; dt < 4; ++dt)
#pragma unroll
    for (int mt = 0; mt < 4; ++mt)
#pragma unroll
      for (int r = 0; r < 4; ++r)
        kp[(wd + dt * 16 + lg * 4 + r) * CDIM + wm + mt * 16 + l15] = (bf16)acc[dt][mt][r];
}

// ---------------------------------------------------------------------------
// k_reduce: sum split-K partials -> ktv bf16 [h][d][m], ksum f32 [h][m]
// ---------------------------------------------------------------------------
__global__ void __launch_bounds__(256) k_reduce(
    const bf16* __restrict__ ktv_part, const float* __restrict__ ksum_part,
    bf16* __restrict__ ktv, float* __restrict__ ksum)
{
  const int b = blockIdx.x;
  if (b < 512) {
    const int t = b * 256 + threadIdx.x;  // < 131072
    float a = 0.f;
    for (int c = 0; c < NCHUNK; ++c) a += (float)ktv_part[c * (NH * CDIM * CDIM) + t];
    ktv[t] = (bf16)a;
  } else {
    const int t = (b - 512) * 256 + threadIdx.x;
    if (t < NH * CDIM) {
      float a = 0.f;
      for (int c = 0; c < NCHUNK; ++c) a += ksum_part[c * (NH * CDIM) + t];
      ksum[t] = a;
    }
  }
}

// ---------------------------------------------------------------------------
// k_out: per 64-row tile, loop heads: qs GEMM -> phi(q) -> numerator GEMM vs ktv,
//        denominator via ksum, fused vss GEMM (W2,b2), head mean, time coord.
// grid: NTOK/64 = 512 blocks, 256 threads
// ---------------------------------------------------------------------------
__global__ void __launch_bounds__(256, 2) k_out(
    const float* __restrict__ query, const float* __restrict__ src,
    const bf16* __restrict__ wq, const float* __restrict__ Wq_b,
    const bf16* __restrict__ ktv, const float* __restrict__ ksum,
    const bf16* __restrict__ w2, const float* __restrict__ b2,
    const float* __restrict__ nscale, float* __restrict__ out)
{
  const int nb = blockIdx.x * 64;
  const int tid = threadIdx.x;
  const int w = tid >> 6, l = tid & 63;
  const int l15 = l & 15, lg = l >> 4;
  const int os = w * 32;

  __shared__ bf16 s_q[64][136];
  __shared__ bf16 s_s[64][136];
  __shared__ bf16 s_phi[64][136];   // [n][m]
  __shared__ float s_red[4][64][3] __attribute__((aligned(16)));
  __shared__ float s_scale[64] __attribute__((aligned(16)));
  __shared__ float s_invden[64] __attribute__((aligned(16)));

  const float inv_ds = 1.f / (fabsf(nscale[0]) + 1e-6f);
  const f32x4 z4 = {0.f, 0.f, 0.f, 0.f};

  // stage query + source tiles
#pragma unroll
  for (int j = 0; j < 8; ++j) {
    const int flat = tid + j * 256;
    const int n = flat >> 5, i4 = flat & 31;
    f32x4 vq = *(const f32x4*)(query + (nb + n) * CDIM + i4 * 4);
    f32x4 vs = *(const f32x4*)(src + (nb + n) * CDIM + i4 * 4);
    bf16x4v bq, bs;
    bq[0] = (bf16)vq[0]; bq[1] = (bf16)vq[1]; bq[2] = (bf16)vq[2]; bq[3] = (bf16)vq[3];
    bs[0] = (bf16)vs[0]; bs[1] = (bf16)vs[1]; bs[2] = (bf16)vs[2]; bs[3] = (bf16)vs[3];
    *(bf16x4v*)&s_q[n][i4 * 4] = bq;
    *(bf16x4v*)&s_s[n][i4 * 4] = bs;
  }

  f32x4 accO[4][2];
#pragma unroll
  for (int nt = 0; nt < 4; ++nt)
#pragma unroll
    for (int ot = 0; ot < 2; ++ot) accO[nt][ot] = z4;

  for (int h = 0; h < NH; ++h) {
    __syncthreads();
    // qs GEMM (M=n, N=o strip, K=i)
    f32x4 accQ[4][2];
#pragma unroll
    for (int nt = 0; nt < 4; ++nt)
#pragma unroll
      for (int ot = 0; ot < 2; ++ot) accQ[nt][ot] = z4;
#pragma unroll
    for (int kk = 0; kk < 4; ++kk) {
      bf16x8v a[4];
#pragma unroll
      for (int nt = 0; nt < 4; ++nt)
        a[nt] = *(const bf16x8v*)&s_q[nt * 16 + l15][kk * 32 + lg * 8];
#pragma unroll
      for (int ot = 0; ot < 2; ++ot) {
        bf16x8v bw = *(const bf16x8v*)(wq + (h * CDIM + os + ot * 16 + l15) * CDIM + kk * 32 + lg * 8);
#pragma unroll
        for (int nt = 0; nt < 4; ++nt)
          accQ[nt][ot] = mfma16(a[nt], bw, accQ[nt][ot]);
      }
    }
    float bQ[2], kw[2], b2v[2];
#pragma unroll
    for (int ot = 0; ot < 2; ++ot) {
      const int o = os + ot * 16 + l15;
      bQ[ot]  = Wq_b[h * CDIM + o];
      kw[ot]  = ksum[h * CDIM + o];
      b2v[ot] = b2[h * CDIM + o];
    }
    // x^2 in place + norms + denominator partial
#pragma unroll
    for (int nt = 0; nt < 4; ++nt)
#pragma unroll
      for (int r = 0; r < 4; ++r) {
        float a2 = 0.f, a4 = 0.f, aT = 0.f;
#pragma unroll
        for (int ot = 0; ot < 2; ++ot) {
          float x = (fmaxf(accQ[nt][ot][r] + bQ[ot], 0.f) + 1e-6f) * inv_ds;
          float x2 = x * x;
          accQ[nt][ot][r] = x2;
          a2 += x2;
          a4 += x2 * x2;
          aT += x2 * kw[ot];
        }
        a2 = xred16(a2);
        a4 = xred16(a4);
        aT = xred16(aT);
        if (l15 == 0) {
          s_red[w][nt * 16 + lg * 4 + r][0] = a2;
          s_red[w][nt * 16 + lg * 4 + r][1] = a4;
          s_red[w][nt * 16 + lg * 4 + r][2] = aT;
        }
      }
    __syncthreads();
    if (tid < 64) {
      float S2 = s_red[0][tid][0] + s_red[1][tid][0] + s_red[2][tid][0] + s_red[3][tid][0];
      float S4 = s_red[0][tid][1] + s_red[1][tid][1] + s_red[2][tid][1] + s_red[3][tid][1];
      float T  = s_red[0][tid][2] + s_red[1][tid][2] + s_red[2][tid][2] + s_red[3][tid][2];
      float scale = sqrtf(S2) / (sqrtf(S4) + 1e-8f);
      s_scale[tid] = scale;
      s_invden[tid] = 1.f / (scale * T + 1e-6f);
    }
    __syncthreads();
    // phi(q) -> LDS [n][m]
#pragma unroll
    for (int nt = 0; nt < 4; ++nt) {
      f32x4 sc = *(const f32x4*)&s_scale[nt * 16 + lg * 4];
#pragma unroll
      for (int ot = 0; ot < 2; ++ot)
#pragma unroll
        for (int r = 0; r < 4; ++r)
          s_phi[nt * 16 + lg * 4 + r][os + ot * 16 + l15] = (bf16)(accQ[nt][ot][r] * sc[r]);
    }
    __syncthreads();
    // numerator GEMM: M=n, N=d strip, K=m; B = ktv[h][d][m]
    f32x4 accN[4][2];
#pragma unroll
    for (int nt = 0; nt < 4; ++nt)
#pragma unroll
      for (int dt = 0; dt < 2; ++dt) accN[nt][dt] = z4;
#pragma unroll
    for (int kk = 0; kk < 4; ++kk) {
      bf16x8v a[4];
#pragma unroll
      for (int nt = 0; nt < 4; ++nt)
        a[nt] = *(const bf16x8v*)&s_phi[nt * 16 + l15][kk * 32 + lg * 8];
#pragma unroll
      for (int dt = 0; dt < 2; ++dt) {
        bf16x8v bk = *(const bf16x8v*)(ktv + (h * CDIM + os + dt * 16 + l15) * CDIM + kk * 32 + lg * 8);
#pragma unroll
        for (int nt = 0; nt < 4; ++nt)
          accN[nt][dt] = mfma16(a[nt], bk, accN[nt][dt]);
      }
    }
#pragma unroll
    for (int nt = 0; nt < 4; ++nt) {
      f32x4 iv = *(const f32x4*)&s_invden[nt * 16 + lg * 4];
#pragma unroll
      for (int dt = 0; dt < 2; ++dt)
#pragma unroll
        for (int r = 0; r < 4; ++r)
          accO[nt][dt][r] = fmaf(accN[nt][dt][r], iv[r], accO[nt][dt][r]);
    }
    // fused vss GEMM straight into accO
#pragma unroll
    for (int kk = 0; kk < 4; ++kk) {
      bf16x8v a[4];
#pragma unroll
      for (int nt = 0; nt < 4; ++nt)
        a[nt] = *(const bf16x8v*)&s_s[nt * 16 + l15][kk * 32 + lg * 8];
#pragma unroll
      for (int ot = 0; ot < 2; ++ot) {
        bf16x8v bw = *(const bf16x8v*)(w2 + (h * CDIM + os + ot * 16 + l15) * CDIM + kk * 32 + lg * 8);
#pragma unroll
        for (int nt = 0; nt < 4; ++nt)
          accO[nt][ot] = mfma16(a[nt], bw, accO[nt][ot]);
      }
    }
#pragma unroll
    for (int nt = 0; nt < 4; ++nt)
#pragma unroll
      for (int ot = 0; ot < 2; ++ot)
#pragma unroll
        for (int r = 0; r < 4; ++r)
          accO[nt][ot][r] += b2v[ot];
  }

  // epilogue: head mean, squared-norm, stores
  float ps[4][4];
#pragma unroll
  for (int nt = 0; nt < 4; ++nt)
#pragma unroll
    for (int r = 0; r < 4; ++r) ps[nt][r] = 0.f;
#pragma unroll
  for (int nt = 0; nt < 4; ++nt)
#pragma unroll
    for (int dt = 0; dt < 2; ++dt)
#pragma unroll
      for (int r = 0; r < 4; ++r) {
        float v = accO[nt][dt][r] * 0.125f;
        accO[nt][dt][r] = v;
        ps[nt][r] += v * v;
      }
#pragma unroll
  for (int nt = 0; nt < 4; ++nt)
#pragma unroll
    for (int r = 0; r < 4; ++r) {
      float t = xred16(ps[nt][r]);
      if (l15 == 0) s_red[w][nt * 16 + lg * 4 + r][0] = t;
    }
#pragma unroll
  for (int nt = 0; nt < 4; ++nt)
#pragma unroll
    for (int dt = 0; dt < 2; ++dt)
#pragma unroll
      for (int r = 0; r < 4; ++r)
        out[(nb + nt * 16 + lg * 4 + r) * 129 + 1 + os + dt * 16 + l15] = accO[nt][dt][r];
  __syncthreads();
  if (tid < 64) {
    float S = 1.0f + s_red[0][tid][0] + s_red[1][tid][0] + s_red[2][tid][0] + s_red[3][tid][0];
    out[(nb + tid) * 129] = sqrtf(S);
  }
}

// ---------------------------------------------------------------------------
extern "C" void kernel_launch(void* const* d_in, const int* in_sizes, int n_in,
                              void* d_out, int out_size, void* d_ws, size_t ws_size,
                              hipStream_t stream) {
  const float* query  = (const float*)d_in[0];
  const float* source = (const float*)d_in[1];
  const float* Wq_w   = (const float*)d_in[2];
  const float* Wq_b   = (const float*)d_in[3];
  const float* Wk_w   = (const float*)d_in[4];
  const float* Wk_b   = (const float*)d_in[5];
  const float* Wv_w   = (const float*)d_in[6];
  const float* Wv_b   = (const float*)d_in[7];
  const float* vmw    = (const float*)d_in[8];
  const float* vmb    = (const float*)d_in[9];
  const float* ns     = (const float*)d_in[10];

  char* ws = (char*)d_ws;
  bf16*  wq        = (bf16*)(ws + 0);         // 262144 B
  bf16*  wk        = (bf16*)(ws + 262144);    // 262144 B
  bf16*  wv        = (bf16*)(ws + 524288);    // 262144 B
  bf16*  w2        = (bf16*)(ws + 786432);    // 262144 B
  float* b2        = (float*)(ws + 1048576);  // 4096 B
  float* ksum      = (float*)(ws + 1052672);  // 4096 B
  bf16*  ktv       = (bf16*)(ws + 1056768);   // 262144 B
  float* ksum_part = (float*)(ws + 1318912);  // 262144 B
  bf16*  ktv_part  = (bf16*)(ws + 1581056);   // 16777216 B  (total ~17.5 MiB)

  k_prep<<<1024, 128, 0, stream>>>(Wq_w, Wk_w, Wv_w, Wv_b, vmw, vmb, wq, wk, wv, w2, b2);
  k_ktv<<<NCHUNK * NH, 256, 0, stream>>>(source, wk, wv, Wk_b, Wv_b, ns, ktv_part, ksum_part);
  k_reduce<<<516, 256, 0, stream>>>(ktv_part, ksum_part, ktv, ksum);
  k_out<<<NTOK / 64, 256, 0, stream>>>(query, source, wq, Wq_b, ktv, ksum, w2, b2, ns, (float*)d_out);
}